// Round 5
// baseline (135.584 us; speedup 1.0000x reference)
//
#include <hip/hip_runtime.h>

// SSIM, N=32 images 512x512 fp32, 11x11 Gaussian (separable via rank-1
// window), zero pad, scalar mean output.
//
// R5: R4 was LDS-bandwidth-bound (11 x ds_read_b128/thread-row = 42us of
// LDS pipe vs 15-20us VALU; VALUBusy 37%). Fix: stage the 2-plane basis
// (s,d) = (x+y, x-y) as float2 — conv is linear, and per-tap s^2, d^2
// recover all four moments:
//   Ms=mx+my, Md=mx-my, Ms2=Ex2+2Exy+Ey2, Md2=Ex2-2Exy+Ey2
//   mx^2+my^2=(Ms^2+Md^2)/2, mx*my=(Ms^2-Md^2)/4,
//   Ex2+Ey2=(Ms2+Md2)/2,     Exy=(Ms2-Md2)/4.
// Window reads: 11 x ds_read_b64 (~6cyc) vs 11 x b128 (12cyc): LDS pipe
// ~20us, VALU ~19-25us — balanced. Skeleton unchanged from R4 (proven):
// TW=128, RROWS=32, 4096 waves = 16/CU, prefetch 1 row ahead, 44-reg
// vertical ring (mod-11 static via 11x unroll), VGPR <= 64, no
// min-waves launch_bounds (R3 spill lesson).

#define IMG_H 512
#define IMG_W 512
#define NIMG  32
#define TW    128              // threads = own columns per block
#define RROWS 32               // output rows per block
#define ITERS (RROWS + 10)     // 42 input rows streamed
#define LDSW  (TW + 10)        // 138 staged cols (5-col halo each side)

#define C1F  1.0e-4f
#define C2F  9.0e-4f
#define EPSF 1.0e-8f

__global__ __launch_bounds__(TW) void ssim_kernel(
    const float* __restrict__ xg, const float* __restrict__ yg,
    const float* __restrict__ wg, float* __restrict__ out)
{
    const int t    = threadIdx.x;       // 0..127
    const int band = blockIdx.x;        // 0..3
    const int chnk = blockIdx.y;        // 0..15
    const int img  = blockIdx.z;        // 0..31
    const int c0   = band * TW;
    const int r0   = chnk * RROWS;

    const float* xb = xg + (size_t)img * (IMG_H * IMG_W);
    const float* yb = yg + (size_t)img * (IMG_H * IMG_W);

    __shared__ float2 ssd[2][LDSW];     // (s, d) per column, double-buffered
    __shared__ float wredS[2];

    // 1D taps = row sums of normalized 2D window -> SGPRs via readfirstlane.
    float rs = 0.f;
    {
        const int lane = t & 63;
        if (lane < 11) {
            #pragma unroll
            for (int j = 0; j < 11; ++j) rs += wg[lane * 11 + j];
        }
    }
    float g[11];
    #pragma unroll
    for (int k = 0; k < 11; ++k) {
        int gi = __shfl(__float_as_int(rs), k, 64);
        g[k] = __int_as_float(__builtin_amdgcn_readfirstlane(gi));
    }

    const int colA = c0 + t;                    // always in [0, IMG_W)
    const int  b2     = (t < 5) ? t : (TW + t); // halo buffer slot (t<10)
    const int  colB   = c0 - 5 + b2;
    const bool hasB   = (t < 10);
    const bool colBok = hasB && ((unsigned)colB < IMG_W);

    // vertical register rings: 4 planes x 11 rows = 44 VGPRs
    float rS[11], rD[11], rS2[11], rD2[11];

    // preload first input row (r0 - 5)
    float lxA, lyA, lxB, lyB;
    {
        const int r = r0 - 5;
        const bool rv = ((unsigned)r < IMG_H);
        const float* xr = xb + (size_t)r * IMG_W;
        const float* yr = yb + (size_t)r * IMG_W;
        lxA = rv ? xr[colA] : 0.f;
        lyA = rv ? yr[colA] : 0.f;
        lxB = (rv && colBok) ? xr[colB] : 0.f;
        lyB = (rv && colBok) ? yr[colB] : 0.f;
    }

    float acc = 0.f;

    for (int ii = 0; ii < 44; ii += 11) {
        #pragma unroll
        for (int s = 0; s < 11; ++s) {
            const int i = ii + s;
            if (i < ITERS) {
                const int pb = i & 1;
                // stage own column (+ halo col for t<10) in (s,d) basis
                ssd[pb][5 + t] = make_float2(lxA + lyA, lxA - lyA);
                if (hasB)
                    ssd[pb][b2] = make_float2(lxB + lyB, lxB - lyB);
                __syncthreads();

                // prefetch next input row (consumed next iteration)
                {
                    const int r = r0 - 4 + i;
                    const bool rv = ((unsigned)r < IMG_H);
                    const float* xr = xb + (size_t)r * IMG_W;
                    const float* yr = yb + (size_t)r * IMG_W;
                    lxA = rv ? xr[colA] : 0.f;
                    lyA = rv ? yr[colA] : 0.f;
                    lxB = (rv && colBok) ? xr[colB] : 0.f;
                    lyB = (rv && colBok) ? yr[colB] : 0.f;
                }

                // horizontal 11-tap conv: per tap load (s,d), square, 4 FMA
                float hS = 0.f, hD = 0.f, hS2 = 0.f, hD2 = 0.f;
                #pragma unroll
                for (int k = 0; k < 11; ++k) {
                    const float2 w = ssd[pb][t + k];
                    hS  = fmaf(g[k], w.x, hS);
                    hD  = fmaf(g[k], w.y, hD);
                    hS2 = fmaf(g[k], w.x * w.x, hS2);
                    hD2 = fmaf(g[k], w.y * w.y, hD2);
                }
                rS[s] = hS; rD[s] = hD; rS2[s] = hS2; rD2[s] = hD2;

                if (i >= 10) {                  // output row r0 + i - 10
                    float mS = 0.f, mD = 0.f, mS2 = 0.f, mD2 = 0.f;
                    #pragma unroll
                    for (int j = 0; j < 11; ++j) {
                        const int sl = (s + 1 + j) % 11;   // static
                        mS  = fmaf(g[j], rS[sl],  mS);
                        mD  = fmaf(g[j], rD[sl],  mD);
                        mS2 = fmaf(g[j], rS2[sl], mS2);
                        mD2 = fmaf(g[j], rD2[sl], mD2);
                    }
                    const float t1   = mS * mS, t2 = mD * mD;
                    const float a    = 0.5f  * (t1 + t2);   // mx^2 + my^2
                    const float muxy = 0.25f * (t1 - t2);   // mx * my
                    const float ep   = 0.5f  * (mS2 + mD2); // Ex2 + Ey2
                    const float eq   = 0.25f * (mS2 - mD2); // Exy
                    const float sxy  = eq - muxy;
                    const float ssum = ep - a;
                    const float num  = fmaf(2.f, muxy, C1F) * fmaf(2.f, sxy, C2F);
                    const float den  = (a + C1F) * (ssum + C2F);
                    float v = num * __builtin_amdgcn_rcpf(den + EPSF);
                    acc += fminf(fmaxf(v, 0.f), 1.f);
                }
            }
        }
    }

    // block reduction: wave shuffle, then 2 slots in LDS, one atomic
    #pragma unroll
    for (int off = 32; off > 0; off >>= 1)
        acc += __shfl_down(acc, off, 64);
    __syncthreads();
    if ((t & 63) == 0) wredS[t >> 6] = acc;
    __syncthreads();
    if (t == 0) {
        const float tot = wredS[0] + wredS[1];
        atomicAdd(out, tot * (1.0f / (float)((size_t)NIMG * IMG_H * IMG_W)));
    }
}

extern "C" void kernel_launch(void* const* d_in, const int* in_sizes, int n_in,
                              void* d_out, int out_size, void* d_ws, size_t ws_size,
                              hipStream_t stream) {
    const float* x = (const float*)d_in[0];
    const float* y = (const float*)d_in[1];
    const float* w = (const float*)d_in[2];
    float* out = (float*)d_out;

    // d_out is re-poisoned to 0xAA before every timed launch; zero it first.
    hipMemsetAsync(out, 0, sizeof(float), stream);

    dim3 grid(IMG_W / TW, IMG_H / RROWS, NIMG);   // (4, 16, 32)
    ssim_kernel<<<grid, dim3(TW), 0, stream>>>(x, y, w, out);
}